// Round 2
// baseline (442.551 us; speedup 1.0000x reference)
//
#include <hip/hip_runtime.h>
#include <math.h>

#define B_SZ 2
#define T_SZ 512
#define D_SZ 64
#define ELEMS 4096            // D*D
#define CHUNK 32              // timesteps per scan block
#define NCHUNK (T_SZ / CHUNK) // 16
#define NROWS (B_SZ * D_SZ)   // 128

// ws layout (bytes)
#define DECAY_OFF  0
#define DECAY_BYTES ((size_t)B_SZ * T_SZ * D_SZ * 4)          // 256 KB
#define FLAGS_OFF  DECAY_BYTES                                 // 262144
#define FLAGS_BYTES ((size_t)NCHUNK * NROWS * 4)               // 8 KB
#define CARRY_OFF  (FLAGS_OFF + 16384)                         // padded
#define CARRY_BYTES ((size_t)NCHUNK * NROWS * D_SZ * 4)        // 512 KB
#define WS_NEEDED  (CARRY_OFF + CARRY_BYTES)

// Kernel 1: per-(b,t) LayerNorm over D*D + affine, row-dot with dt_w,
// softplus, decay = exp(softplus(dot+dt_b) * -exp(log_A[r])).
__global__ __launch_bounds__(256) void ln_dt_kernel(
    const float* __restrict__ x, const float* __restrict__ log_A,
    const float* __restrict__ dt_w, const float* __restrict__ dt_b,
    const float* __restrict__ ln_w, const float* __restrict__ ln_b,
    float* __restrict__ xn_out, float* __restrict__ decay_out)
{
    const int bt  = blockIdx.x;            // 0..B*T-1
    const int tid = threadIdx.x;           // 0..255
    const size_t base = (size_t)bt * ELEMS;

    float4 v[4];
    float sum = 0.f, sumsq = 0.f;
    const float4* xv4 = reinterpret_cast<const float4*>(x + base);
#pragma unroll
    for (int k = 0; k < 4; ++k) {
        v[k] = xv4[tid + 256 * k];
        sum   += v[k].x + v[k].y + v[k].z + v[k].w;
        sumsq += v[k].x * v[k].x + v[k].y * v[k].y + v[k].z * v[k].z + v[k].w * v[k].w;
    }

    __shared__ float red0[4], red1[4];
#pragma unroll
    for (int off = 32; off; off >>= 1) {
        sum   += __shfl_down(sum, off);
        sumsq += __shfl_down(sumsq, off);
    }
    const int wave = tid >> 6;
    if ((tid & 63) == 0) { red0[wave] = sum; red1[wave] = sumsq; }
    __syncthreads();
    sum   = red0[0] + red0[1] + red0[2] + red0[3];
    sumsq = red1[0] + red1[1] + red1[2] + red1[3];

    const float mu = sum * (1.f / ELEMS);
    const float var = sumsq * (1.f / ELEMS) - mu * mu;
    const float rs = rsqrtf(var + 1e-5f);

    const float4* w4p = reinterpret_cast<const float4*>(ln_w);
    const float4* b4p = reinterpret_cast<const float4*>(ln_b);
    const float4* dw4 = reinterpret_cast<const float4*>(dt_w);
    float4* xo4 = reinterpret_cast<float4*>(xn_out + base);
    float dot[4] = {0.f, 0.f, 0.f, 0.f};
#pragma unroll
    for (int k = 0; k < 4; ++k) {
        const int f = tid + 256 * k;
        float4 w4 = w4p[f];
        float4 b4 = b4p[f];
        float4 xn;
        xn.x = (v[k].x - mu) * rs * w4.x + b4.x;
        xn.y = (v[k].y - mu) * rs * w4.y + b4.y;
        xn.z = (v[k].z - mu) * rs * w4.z + b4.z;
        xn.w = (v[k].w - mu) * rs * w4.w + b4.w;
        xo4[f] = xn;
        float4 wv = dw4[f & 15];
        dot[k] += xn.x * wv.x + xn.y * wv.y + xn.z * wv.z + xn.w * wv.w;
    }

#pragma unroll
    for (int m = 1; m <= 8; m <<= 1) {
#pragma unroll
        for (int k = 0; k < 4; ++k) dot[k] += __shfl_xor(dot[k], m);
    }

    if ((tid & 15) == 0) {
        const int m = tid >> 4;
        const float db = dt_b[0];
#pragma unroll
        for (int k = 0; k < 4; ++k) {
            const int r = m + 16 * k;
            const float z = dot[k] + db;
            const float dt = (z > 20.f) ? z : log1pf(expf(z));
            const float A = -expf(log_A[r]);
            decay_out[(size_t)bt * D_SZ + r] = expf(dt * A);
        }
    }
}

// Kernel 2: chained stream-scan. Grid = NCHUNK*NROWS single-wave blocks,
// blockIdx = k*NROWS + row (chunk index slow -> predecessors dispatch first).
// lane = column c. Carry chain per row via release/acquire flags (agent scope).
__global__ __launch_bounds__(64) void scan_chain_kernel(
    const float* __restrict__ decay, float* __restrict__ xn_io,
    float* __restrict__ carries, int* __restrict__ flags)
{
    const int lane = threadIdx.x;           // column c
    const int k    = blockIdx.x / NROWS;    // chunk index
    const int row  = blockIdx.x - k * NROWS;
    const int b = row >> 6;
    const int r = row & 63;
    const int t0 = k * CHUNK;

    // lane t (< CHUNK) holds d_{t0+t} for this row
    float d = 1.0f;
    if (lane < CHUNK)
        d = decay[((size_t)(b * T_SZ + t0 + lane)) * D_SZ + r];

    // inclusive cumprod across lanes 0..CHUNK-1
    float cp = d;
#pragma unroll
    for (int off = 1; off < CHUNK; off <<= 1) {
        float o = __shfl_up(cp, off);
        if (lane >= off) cp *= o;
    }
    const float P = __shfl(cp, CHUNK - 1);

    const float* xp = xn_io + (size_t)(b * T_SZ + t0) * ELEMS + r * D_SZ + lane;
    float v[CHUNK];
#pragma unroll
    for (int t = 0; t < CHUNK; ++t) v[t] = xp[(size_t)t * ELEMS];

    float S = 0.f;
#pragma unroll
    for (int t = 0; t < CHUNK; ++t) {
        S = fmaf(S, __shfl(d, t), v[t]);
        v[t] = S;
    }

    // resolve carry-in from predecessor chunk
    float Cin = 0.f;
    if (k > 0) {
        const int pidx = (k - 1) * NROWS + row;
        while (__hip_atomic_load(&flags[pidx], __ATOMIC_ACQUIRE,
                                 __HIP_MEMORY_SCOPE_AGENT) == 0) {
            __builtin_amdgcn_s_sleep(1);
        }
        Cin = carries[(size_t)pidx * D_SZ + lane];
    }
    // publish inclusive carry ASAP
    if (k < NCHUNK - 1) {
        const int idx = k * NROWS + row;
        carries[(size_t)idx * D_SZ + lane] = S + P * Cin;  // S == v[CHUNK-1]
        __hip_atomic_store(&flags[idx], 1, __ATOMIC_RELEASE,
                           __HIP_MEMORY_SCOPE_AGENT);
    }

    float* op = xn_io + (size_t)(b * T_SZ + t0) * ELEMS + r * D_SZ + lane;
#pragma unroll
    for (int t = 0; t < CHUNK; ++t)
        op[(size_t)t * ELEMS] = v[t] + __shfl(cp, t) * Cin;
}

// Fallback: serial per-(b,r) scan (used only if ws is too small for the chain).
__global__ __launch_bounds__(256) void scan_kernel(
    const float* __restrict__ decay, float* __restrict__ xn_io)
{
    const int gtid = blockIdx.x * blockDim.x + threadIdx.x;
    const int wid  = gtid >> 6;
    const int lane = threadIdx.x & 63;
    const int b = wid >> 6;
    const int r = wid & 63;

    const float* dptr = decay + (size_t)b * (T_SZ * D_SZ) + r;
    float* p = xn_io + (size_t)b * ((size_t)T_SZ * ELEMS) + r * D_SZ + lane;

    float S = 0.f;
    for (int t = 0; t < T_SZ; ++t) {
        const float dd = dptr[(size_t)t * D_SZ];
        const float xv = p[(size_t)t * ELEMS];
        S = fmaf(S, dd, xv);
        p[(size_t)t * ELEMS] = S;
    }
}

extern "C" void kernel_launch(void* const* d_in, const int* in_sizes, int n_in,
                              void* d_out, int out_size, void* d_ws, size_t ws_size,
                              hipStream_t stream) {
    const float* x     = (const float*)d_in[0];
    const float* log_A = (const float*)d_in[1];
    const float* dt_w  = (const float*)d_in[2];
    const float* dt_b  = (const float*)d_in[3];
    const float* ln_w  = (const float*)d_in[4];
    const float* ln_b  = (const float*)d_in[5];
    float* out   = (float*)d_out;
    float* decay = (float*)((char*)d_ws + DECAY_OFF);

    if (ws_size >= WS_NEEDED) {
        int*   flags   = (int*)((char*)d_ws + FLAGS_OFF);
        float* carries = (float*)((char*)d_ws + CARRY_OFF);
        hipMemsetAsync(flags, 0, FLAGS_BYTES, stream);
        ln_dt_kernel<<<B_SZ * T_SZ, 256, 0, stream>>>(
            x, log_A, dt_w, dt_b, ln_w, ln_b, out, decay);
        scan_chain_kernel<<<NCHUNK * NROWS, 64, 0, stream>>>(
            decay, out, carries, flags);
    } else {
        ln_dt_kernel<<<B_SZ * T_SZ, 256, 0, stream>>>(
            x, log_A, dt_w, dt_b, ln_w, ln_b, out, decay);
        scan_kernel<<<(B_SZ * D_SZ * 64) / 256, 256, 0, stream>>>(decay, out);
    }
}

// Round 3
// 32.235 us; speedup vs baseline: 13.7290x; 13.7290x over previous
//
#include <hip/hip_runtime.h>
#include <math.h>

#define B_SZ 2
#define T_SZ 512
#define D_SZ 64
#define ELEMS 4096            // D*D
#define WCHUNK 64             // timesteps per wave in scan kernel
#define NWAVE 8               // waves per scan block (NWAVE*WCHUNK == T_SZ)

// Kernel 1: per-(b,t) LayerNorm over D*D + affine, row-dot with dt_w,
// softplus, decay = exp(softplus(dot+dt_b) * -exp(log_A[r])).
// xn -> xn_out (= d_out), decay -> decay_out (d_ws).
__global__ __launch_bounds__(256) void ln_dt_kernel(
    const float* __restrict__ x, const float* __restrict__ log_A,
    const float* __restrict__ dt_w, const float* __restrict__ dt_b,
    const float* __restrict__ ln_w, const float* __restrict__ ln_b,
    float* __restrict__ xn_out, float* __restrict__ decay_out)
{
    const int bt  = blockIdx.x;            // 0..B*T-1
    const int tid = threadIdx.x;           // 0..255
    const size_t base = (size_t)bt * ELEMS;

    float4 v[4];
    float sum = 0.f, sumsq = 0.f;
    const float4* xv4 = reinterpret_cast<const float4*>(x + base);
#pragma unroll
    for (int k = 0; k < 4; ++k) {
        v[k] = xv4[tid + 256 * k];
        sum   += v[k].x + v[k].y + v[k].z + v[k].w;
        sumsq += v[k].x * v[k].x + v[k].y * v[k].y + v[k].z * v[k].z + v[k].w * v[k].w;
    }

    __shared__ float red0[4], red1[4];
#pragma unroll
    for (int off = 32; off; off >>= 1) {
        sum   += __shfl_down(sum, off);
        sumsq += __shfl_down(sumsq, off);
    }
    const int wave = tid >> 6;
    if ((tid & 63) == 0) { red0[wave] = sum; red1[wave] = sumsq; }
    __syncthreads();
    sum   = red0[0] + red0[1] + red0[2] + red0[3];
    sumsq = red1[0] + red1[1] + red1[2] + red1[3];

    const float mu = sum * (1.f / ELEMS);
    const float var = sumsq * (1.f / ELEMS) - mu * mu;
    const float rs = rsqrtf(var + 1e-5f);

    const float4* w4p = reinterpret_cast<const float4*>(ln_w);
    const float4* b4p = reinterpret_cast<const float4*>(ln_b);
    const float4* dw4 = reinterpret_cast<const float4*>(dt_w);
    float4* xo4 = reinterpret_cast<float4*>(xn_out + base);
    float dot[4] = {0.f, 0.f, 0.f, 0.f};
#pragma unroll
    for (int k = 0; k < 4; ++k) {
        const int f = tid + 256 * k;
        float4 w4 = w4p[f];
        float4 b4 = b4p[f];
        float4 xn;
        xn.x = (v[k].x - mu) * rs * w4.x + b4.x;
        xn.y = (v[k].y - mu) * rs * w4.y + b4.y;
        xn.z = (v[k].z - mu) * rs * w4.z + b4.z;
        xn.w = (v[k].w - mu) * rs * w4.w + b4.w;
        xo4[f] = xn;
        float4 wv = dw4[f & 15];
        dot[k] += xn.x * wv.x + xn.y * wv.y + xn.z * wv.z + xn.w * wv.w;
    }

#pragma unroll
    for (int m = 1; m <= 8; m <<= 1) {
#pragma unroll
        for (int k = 0; k < 4; ++k) dot[k] += __shfl_xor(dot[k], m);
    }

    if ((tid & 15) == 0) {
        const int m = tid >> 4;
        const float db = dt_b[0];
#pragma unroll
        for (int k = 0; k < 4; ++k) {
            const int r = m + 16 * k;
            const float z = dot[k] + db;
            const float dt = (z > 20.f) ? z : log1pf(expf(z));
            const float A = -expf(log_A[r]);
            decay_out[(size_t)bt * D_SZ + r] = expf(dt * A);
        }
    }
}

// Kernel 2: one block per row (b,r). 8 waves x 64 lanes; wave w owns
// timesteps [w*64, w*64+64), lane = column c. Local scan in registers,
// cross-wave carry via LDS + __syncthreads (single CU, no global sync).
__global__ __launch_bounds__(NWAVE * 64) void scan_row_kernel(
    const float* __restrict__ decay, float* __restrict__ xn_io)
{
    const int lane = threadIdx.x & 63;     // column c
    const int w    = threadIdx.x >> 6;     // wave id, 0..7
    const int row  = blockIdx.x;           // 0..127
    const int b = row >> 6;
    const int r = row & 63;
    const int t0 = w * WCHUNK;

    // lane l holds d_{t0+l} for this row
    const float d = decay[(size_t)(b * T_SZ + t0 + lane) * D_SZ + r];

    // load this wave's 64 timesteps (one column per lane)
    const size_t basep = ((size_t)(b * T_SZ + t0) * D_SZ + r) * D_SZ + lane;
    float v[WCHUNK];
#pragma unroll
    for (int t = 0; t < WCHUNK; ++t)
        v[t] = xn_io[basep + (size_t)t * ELEMS];

    // local inclusive scan: S_t = d_t * S_{t-1} + x_t
    float S = 0.f;
#pragma unroll
    for (int t = 0; t < WCHUNK; ++t) {
        S = fmaf(S, __shfl(d, t), v[t]);
        v[t] = S;
    }

    // full product of d over this wave's 64 steps
    float P = d;
#pragma unroll
    for (int off = 1; off < 64; off <<= 1)
        P *= __shfl_xor(P, off);

    __shared__ float sS[NWAVE][64];
    __shared__ float sP[NWAVE];
    sS[w][lane] = S;
    if (lane == 0) sP[w] = P;
    __syncthreads();

    // carry-in for this wave: C = fold over waves j < w of C = S_j + P_j*C
    float Cin = 0.f;
    for (int j = 0; j < w; ++j)
        Cin = fmaf(sP[j], Cin, sS[j][lane]);

    // apply carry and write: out_t = v_t + cumprod(d)_t * Cin
    float rp = 1.f;
#pragma unroll
    for (int t = 0; t < WCHUNK; ++t) {
        rp *= __shfl(d, t);
        xn_io[basep + (size_t)t * ELEMS] = fmaf(rp, Cin, v[t]);
    }
}

extern "C" void kernel_launch(void* const* d_in, const int* in_sizes, int n_in,
                              void* d_out, int out_size, void* d_ws, size_t ws_size,
                              hipStream_t stream) {
    const float* x     = (const float*)d_in[0];
    const float* log_A = (const float*)d_in[1];
    const float* dt_w  = (const float*)d_in[2];
    const float* dt_b  = (const float*)d_in[3];
    const float* ln_w  = (const float*)d_in[4];
    const float* ln_b  = (const float*)d_in[5];
    float* out   = (float*)d_out;
    float* decay = (float*)d_ws;   // B*T*D floats = 256 KB

    ln_dt_kernel<<<B_SZ * T_SZ, 256, 0, stream>>>(
        x, log_A, dt_w, dt_b, ln_w, ln_b, out, decay);

    scan_row_kernel<<<B_SZ * D_SZ, NWAVE * 64, 0, stream>>>(decay, out);
}

// Round 4
// 24.086 us; speedup vs baseline: 18.3741x; 1.3383x over previous
//
#include <hip/hip_runtime.h>
#include <math.h>

#define B_SZ 2
#define T_SZ 512
#define D_SZ 64
#define ELEMS 4096            // D*D
#define NW2 8                 // waves per scan block
#define TCH 64                // timesteps per wave (NW2*TCH == T_SZ)

// ws layout: decay_t [B][D][T] floats at 0 (256 KB); stats float2[B*T] at 256K (8 KB)
#define DECAY_BYTES ((size_t)B_SZ * D_SZ * T_SZ * 4)
#define STATS_OFF   DECAY_BYTES

// Kernel 1: per-(b,t) LayerNorm stats over D*D + row-dot with dt_w, softplus,
// decay = exp(softplus(dot+dt_b) * -exp(log_A[r])). Writes decay (transposed
// [b][r][t]) and stats (mu, rs). Does NOT write xn.
__global__ __launch_bounds__(256) void ln_dt_kernel(
    const float* __restrict__ x, const float* __restrict__ log_A,
    const float* __restrict__ dt_w, const float* __restrict__ dt_b,
    const float* __restrict__ ln_w, const float* __restrict__ ln_b,
    float* __restrict__ decay_t, float2* __restrict__ stats)
{
    const int bt  = blockIdx.x;            // 0..B*T-1
    const int tid = threadIdx.x;           // 0..255
    const size_t base = (size_t)bt * ELEMS;

    float4 v[4];
    float sum = 0.f, sumsq = 0.f;
    const float4* xv4 = reinterpret_cast<const float4*>(x + base);
#pragma unroll
    for (int k = 0; k < 4; ++k) {
        v[k] = xv4[tid + 256 * k];
        sum   += v[k].x + v[k].y + v[k].z + v[k].w;
        sumsq += v[k].x * v[k].x + v[k].y * v[k].y + v[k].z * v[k].z + v[k].w * v[k].w;
    }

    __shared__ float red0[4], red1[4];
#pragma unroll
    for (int off = 32; off; off >>= 1) {
        sum   += __shfl_down(sum, off);
        sumsq += __shfl_down(sumsq, off);
    }
    const int wave = tid >> 6;
    if ((tid & 63) == 0) { red0[wave] = sum; red1[wave] = sumsq; }
    __syncthreads();
    sum   = red0[0] + red0[1] + red0[2] + red0[3];
    sumsq = red1[0] + red1[1] + red1[2] + red1[3];

    const float mu = sum * (1.f / ELEMS);
    const float var = sumsq * (1.f / ELEMS) - mu * mu;
    const float rs = rsqrtf(var + 1e-5f);

    // dot of normalized row r with dt_w (xn computed on the fly, not stored)
    const float4* w4p = reinterpret_cast<const float4*>(ln_w);
    const float4* b4p = reinterpret_cast<const float4*>(ln_b);
    const float4* dw4 = reinterpret_cast<const float4*>(dt_w);
    float dot[4] = {0.f, 0.f, 0.f, 0.f};
#pragma unroll
    for (int k = 0; k < 4; ++k) {
        const int f = tid + 256 * k;
        float4 w4 = w4p[f];
        float4 b4 = b4p[f];
        float4 xn;
        xn.x = (v[k].x - mu) * rs * w4.x + b4.x;
        xn.y = (v[k].y - mu) * rs * w4.y + b4.y;
        xn.z = (v[k].z - mu) * rs * w4.z + b4.z;
        xn.w = (v[k].w - mu) * rs * w4.w + b4.w;
        float4 wv = dw4[f & 15];
        dot[k] += xn.x * wv.x + xn.y * wv.y + xn.z * wv.z + xn.w * wv.w;
    }

#pragma unroll
    for (int m = 1; m <= 8; m <<= 1) {
#pragma unroll
        for (int k = 0; k < 4; ++k) dot[k] += __shfl_xor(dot[k], m);
    }

    if (tid == 0) stats[bt] = make_float2(mu, rs);

    if ((tid & 15) == 0) {
        const int m = tid >> 4;
        const float db = dt_b[0];
        const int b = bt >> 9;           // bt / T_SZ
        const int t = bt & (T_SZ - 1);
#pragma unroll
        for (int k = 0; k < 4; ++k) {
            const int r = m + 16 * k;
            const float z = dot[k] + db;
            const float dt = (z > 20.f) ? z : log1pf(expf(z));
            const float A = -expf(log_A[r]);
            decay_t[((size_t)(b * D_SZ + r)) * T_SZ + t] = expf(dt * A);
        }
    }
}

// Kernel 2: one block per row (b,r). 8 waves x 64 lanes; wave w owns
// timesteps [w*64, w*64+64), lane = column c. Applies LN+affine on the fly
// (from stats), scans in registers. Decay/stats read from LDS as broadcast
// scalars (no shuffles). Cross-wave carry via LDS.
__global__ __launch_bounds__(NW2 * 64) void scan_fused_kernel(
    const float* __restrict__ x, const float2* __restrict__ stats,
    const float* __restrict__ decay_t,
    const float* __restrict__ ln_w, const float* __restrict__ ln_b,
    float* __restrict__ out)
{
    const int tid  = threadIdx.x;
    const int lane = tid & 63;            // column c
    const int w    = tid >> 6;            // wave id 0..7
    const int row  = blockIdx.x;          // 0..127
    const int b = row >> 6;
    const int r = row & 63;

    __shared__ float  sd[T_SZ];           // decay for this row, all t
    __shared__ float2 sst[T_SZ];          // (mu, rs) per t
    __shared__ float  sS[NW2][64];
    __shared__ float  sP[NW2];

    if (tid < T_SZ) {
        sd[tid]  = decay_t[(size_t)row * T_SZ + tid];
        sst[tid] = stats[(size_t)b * T_SZ + tid];
    }
    const float wr = ln_w[r * D_SZ + lane];
    const float br = ln_b[r * D_SZ + lane];
    __syncthreads();

    const int t0 = w * TCH;
    const float* xp = x + ((size_t)(b * T_SZ + t0) * D_SZ + r) * D_SZ + lane;

    // load + normalize + local inclusive scan (S_t = d_t*S_{t-1} + xn_t)
    float v[TCH];
    float S = 0.f;
#pragma unroll
    for (int i = 0; i < TCH; ++i) {
        const float  xv = xp[(size_t)i * ELEMS];
        const float2 st = sst[t0 + i];
        const float  xn = fmaf((xv - st.x) * st.y, wr, br);
        S = fmaf(S, sd[t0 + i], xn);
        v[i] = S;
    }

    // product of decays over this wave's chunk (uniform scalar chain)
    float P = 1.f;
#pragma unroll
    for (int i = 0; i < TCH; ++i) P *= sd[t0 + i];

    sS[w][lane] = S;
    if (lane == 0) sP[w] = P;
    __syncthreads();

    // carry-in: fold C = S_j + P_j*C over waves j < w
    float Cin = 0.f;
    for (int j = 0; j < w; ++j)
        Cin = fmaf(sP[j], Cin, sS[j][lane]);

    // apply carry and write: out_t = v_t + cumprod(d)_t * Cin
    float* op = out + ((size_t)(b * T_SZ + t0) * D_SZ + r) * D_SZ + lane;
    float rp = 1.f;
#pragma unroll
    for (int i = 0; i < TCH; ++i) {
        rp *= sd[t0 + i];
        op[(size_t)i * ELEMS] = fmaf(rp, Cin, v[i]);
    }
}

extern "C" void kernel_launch(void* const* d_in, const int* in_sizes, int n_in,
                              void* d_out, int out_size, void* d_ws, size_t ws_size,
                              hipStream_t stream) {
    const float* x     = (const float*)d_in[0];
    const float* log_A = (const float*)d_in[1];
    const float* dt_w  = (const float*)d_in[2];
    const float* dt_b  = (const float*)d_in[3];
    const float* ln_w  = (const float*)d_in[4];
    const float* ln_b  = (const float*)d_in[5];
    float* out     = (float*)d_out;
    float* decay_t = (float*)d_ws;
    float2* stats  = (float2*)((char*)d_ws + STATS_OFF);

    ln_dt_kernel<<<B_SZ * T_SZ, 256, 0, stream>>>(
        x, log_A, dt_w, dt_b, ln_w, ln_b, decay_t, stats);

    scan_fused_kernel<<<B_SZ * D_SZ, NW2 * 64, 0, stream>>>(
        x, stats, decay_t, ln_w, ln_b, out);
}